// Round 2
// baseline (2096.096 us; speedup 1.0000x reference)
//
#include <hip/hip_runtime.h>
#include <hip/hip_bf16.h>
#include <math.h>

// GGNN binary classifier: s=4096, N=4 nodes, 8 GRU steps, MLP head.
// Round 2: bf16-compress W_ih/W_hh once (fused into GRU step 0), steps 1-7
// read bf16 => HBM traffic 4.83 GB -> 3.3 GB.
//
// Workspace layout:
//   Wib:  uint4[12288*1024]  (bf16 W_ih, row-major, 8 bf16 per uint4 chunk)
//   Whhb: uint4[12288*512]   (bf16 W_hh)
//   h state: float4[4096] ping-pong, h_t[k] = {h[node0..3][k]}
//   a_t:  float4[8192]
//   enc:  float[16384], x1: float[4096]

#define S 4096

__device__ __forceinline__ float wave_reduce_add(float v) {
#pragma unroll
    for (int off = 32; off > 0; off >>= 1) v += __shfl_down(v, off, 64);
    return v;
}

// pack two fp32 -> two bf16 (round-to-nearest-even), lo in low 16 bits
__device__ __forceinline__ unsigned pack_bf16_rn(float lo, float hi) {
    unsigned a = __float_as_uint(lo);
    unsigned b = __float_as_uint(hi);
    a = (a + 0x7FFFu + ((a >> 16) & 1u)) >> 16;
    b = (b + 0x7FFFu + ((b >> 16) & 1u)) & 0xFFFF0000u;
    return a | b;
}
__device__ __forceinline__ float bf_lo(unsigned u) { return __uint_as_float(u << 16); }
__device__ __forceinline__ float bf_hi(unsigned u) { return __uint_as_float(u & 0xFFFF0000u); }

__global__ void init_h_k(const float* __restrict__ ann, float4* __restrict__ h) {
    int k = blockIdx.x * 256 + threadIdx.x;
    float4 o;
    o.x = ann[k];
    o.y = ann[S + k];
    o.z = ann[2 * S + k];
    o.w = ann[3 * S + k];
    h[k] = o;
}

__global__ void compute_a_k(const float* __restrict__ Aout, const float* __restrict__ Ain,
                            const float4* __restrict__ h, float4* __restrict__ a) {
    int k = blockIdx.x * 256 + threadIdx.x;  // 0..8191
    const float* M = (k < S) ? Aout : Ain;
    int kk = k & (S - 1);
    float4 hv = h[kk];
    float4 o;
    o.x = M[0]  * hv.x + M[1]  * hv.y + M[2]  * hv.z + M[3]  * hv.w;
    o.y = M[4]  * hv.x + M[5]  * hv.y + M[6]  * hv.z + M[7]  * hv.w;
    o.z = M[8]  * hv.x + M[9]  * hv.y + M[10] * hv.z + M[11] * hv.w;
    o.w = M[12] * hv.x + M[13] * hv.y + M[14] * hv.z + M[15] * hv.w;
    a[k] = o;
}

// Shared GRU epilogue: block-reduce 24 partials, apply gates, write hnext[c].
__device__ __forceinline__ void gru_epilogue(
    float accI[3][4], float accH[3][4], int c, int t,
    const float4* hcur, float4* hnext) {
    __shared__ float red[4][24];
    int lane = t & 63, wid = t >> 6;
#pragma unroll
    for (int g = 0; g < 3; g++) {
#pragma unroll
        for (int n = 0; n < 4; n++) {
            float vI = wave_reduce_add(accI[g][n]);
            float vH = wave_reduce_add(accH[g][n]);
            if (lane == 0) {
                red[wid][g * 4 + n] = vI;
                red[wid][12 + g * 4 + n] = vH;
            }
        }
    }
    __syncthreads();
    if (t < 4) {
        int n = t;
        float I[3], H[3];
#pragma unroll
        for (int g = 0; g < 3; g++) {
            I[g] = red[0][g * 4 + n] + red[1][g * 4 + n] + red[2][g * 4 + n] + red[3][g * 4 + n];
            H[g] = red[0][12 + g * 4 + n] + red[1][12 + g * 4 + n] + red[2][12 + g * 4 + n] + red[3][12 + g * 4 + n];
        }
        float r = 1.f / (1.f + expf(-(I[0] + H[0])));
        float z = 1.f / (1.f + expf(-(I[1] + H[1])));
        float nn = tanhf(I[2] + r * H[2]);
        float hv = ((const float*)hcur)[c * 4 + n];
        ((float*)hnext)[c * 4 + n] = (1.f - z) * nn + z * hv;
    }
}

// Step 0: fp32 weights, fused bf16 conversion write-out.
__global__ __launch_bounds__(256) void gru_conv_k(
    const float* __restrict__ Wih, const float* __restrict__ Whh,
    uint4* __restrict__ Wib, uint4* __restrict__ Whhb,
    const float4* __restrict__ a, const float4* __restrict__ hcur,
    float4* __restrict__ hnext) {
    const int c = blockIdx.x;
    const int t = threadIdx.x;

    float accI[3][4], accH[3][4];
#pragma unroll
    for (int g = 0; g < 3; g++)
#pragma unroll
        for (int n = 0; n < 4; n++) { accI[g][n] = 0.f; accH[g][n] = 0.f; }

    const float4* Wi[3];
    uint4* Wo[3];
#pragma unroll
    for (int g = 0; g < 3; g++) {
        Wi[g] = (const float4*)(Wih + (size_t)(g * S + c) * (2 * S));
        Wo[g] = Wib + (size_t)(g * S + c) * 1024;
    }
#pragma unroll 1
    for (int i = 0; i < 4; i++) {
        int jc = t + 256 * i;  // chunk of 8 scalars, 0..1023
        float4 av[8];
#pragma unroll
        for (int m = 0; m < 8; m++) av[m] = a[8 * jc + m];
#pragma unroll
        for (int g = 0; g < 3; g++) {
            float4 w0 = Wi[g][2 * jc];
            float4 w1 = Wi[g][2 * jc + 1];
            uint4 p;
            p.x = pack_bf16_rn(w0.x, w0.y);
            p.y = pack_bf16_rn(w0.z, w0.w);
            p.z = pack_bf16_rn(w1.x, w1.y);
            p.w = pack_bf16_rn(w1.z, w1.w);
            Wo[g][jc] = p;
            accI[g][0] += w0.x * av[0].x + w0.y * av[1].x + w0.z * av[2].x + w0.w * av[3].x
                        + w1.x * av[4].x + w1.y * av[5].x + w1.z * av[6].x + w1.w * av[7].x;
            accI[g][1] += w0.x * av[0].y + w0.y * av[1].y + w0.z * av[2].y + w0.w * av[3].y
                        + w1.x * av[4].y + w1.y * av[5].y + w1.z * av[6].y + w1.w * av[7].y;
            accI[g][2] += w0.x * av[0].z + w0.y * av[1].z + w0.z * av[2].z + w0.w * av[3].z
                        + w1.x * av[4].z + w1.y * av[5].z + w1.z * av[6].z + w1.w * av[7].z;
            accI[g][3] += w0.x * av[0].w + w0.y * av[1].w + w0.z * av[2].w + w0.w * av[3].w
                        + w1.x * av[4].w + w1.y * av[5].w + w1.z * av[6].w + w1.w * av[7].w;
        }
    }

    const float4* Wh[3];
    uint4* Who[3];
#pragma unroll
    for (int g = 0; g < 3; g++) {
        Wh[g] = (const float4*)(Whh + (size_t)(g * S + c) * S);
        Who[g] = Whhb + (size_t)(g * S + c) * 512;
    }
#pragma unroll 1
    for (int i = 0; i < 2; i++) {
        int jc = t + 256 * i;  // 0..511
        float4 hv[8];
#pragma unroll
        for (int m = 0; m < 8; m++) hv[m] = hcur[8 * jc + m];
#pragma unroll
        for (int g = 0; g < 3; g++) {
            float4 w0 = Wh[g][2 * jc];
            float4 w1 = Wh[g][2 * jc + 1];
            uint4 p;
            p.x = pack_bf16_rn(w0.x, w0.y);
            p.y = pack_bf16_rn(w0.z, w0.w);
            p.z = pack_bf16_rn(w1.x, w1.y);
            p.w = pack_bf16_rn(w1.z, w1.w);
            Who[g][jc] = p;
            accH[g][0] += w0.x * hv[0].x + w0.y * hv[1].x + w0.z * hv[2].x + w0.w * hv[3].x
                        + w1.x * hv[4].x + w1.y * hv[5].x + w1.z * hv[6].x + w1.w * hv[7].x;
            accH[g][1] += w0.x * hv[0].y + w0.y * hv[1].y + w0.z * hv[2].y + w0.w * hv[3].y
                        + w1.x * hv[4].y + w1.y * hv[5].y + w1.z * hv[6].y + w1.w * hv[7].y;
            accH[g][2] += w0.x * hv[0].z + w0.y * hv[1].z + w0.z * hv[2].z + w0.w * hv[3].z
                        + w1.x * hv[4].z + w1.y * hv[5].z + w1.z * hv[6].z + w1.w * hv[7].z;
            accH[g][3] += w0.x * hv[0].w + w0.y * hv[1].w + w0.z * hv[2].w + w0.w * hv[3].w
                        + w1.x * hv[4].w + w1.y * hv[5].w + w1.z * hv[6].w + w1.w * hv[7].w;
        }
    }

    gru_epilogue(accI, accH, c, t, hcur, hnext);
}

// Steps 1-7: bf16 weights (half the HBM traffic).
#define DOT8(ACC, W, AV)                                                                   \
    ACC[0] += bf_lo(W.x) * AV[0].x + bf_hi(W.x) * AV[1].x + bf_lo(W.y) * AV[2].x +         \
              bf_hi(W.y) * AV[3].x + bf_lo(W.z) * AV[4].x + bf_hi(W.z) * AV[5].x +         \
              bf_lo(W.w) * AV[6].x + bf_hi(W.w) * AV[7].x;                                 \
    ACC[1] += bf_lo(W.x) * AV[0].y + bf_hi(W.x) * AV[1].y + bf_lo(W.y) * AV[2].y +         \
              bf_hi(W.y) * AV[3].y + bf_lo(W.z) * AV[4].y + bf_hi(W.z) * AV[5].y +         \
              bf_lo(W.w) * AV[6].y + bf_hi(W.w) * AV[7].y;                                 \
    ACC[2] += bf_lo(W.x) * AV[0].z + bf_hi(W.x) * AV[1].z + bf_lo(W.y) * AV[2].z +         \
              bf_hi(W.y) * AV[3].z + bf_lo(W.z) * AV[4].z + bf_hi(W.z) * AV[5].z +         \
              bf_lo(W.w) * AV[6].z + bf_hi(W.w) * AV[7].z;                                 \
    ACC[3] += bf_lo(W.x) * AV[0].w + bf_hi(W.x) * AV[1].w + bf_lo(W.y) * AV[2].w +         \
              bf_hi(W.y) * AV[3].w + bf_lo(W.z) * AV[4].w + bf_hi(W.z) * AV[5].w +         \
              bf_lo(W.w) * AV[6].w + bf_hi(W.w) * AV[7].w;

__global__ __launch_bounds__(256, 4) void gru_bf16_k(
    const uint4* __restrict__ Wib, const uint4* __restrict__ Whhb,
    const float4* __restrict__ a, const float4* __restrict__ hcur,
    float4* __restrict__ hnext) {
    const int c = blockIdx.x;
    const int t = threadIdx.x;

    float accI[3][4], accH[3][4];
#pragma unroll
    for (int g = 0; g < 3; g++)
#pragma unroll
        for (int n = 0; n < 4; n++) { accI[g][n] = 0.f; accH[g][n] = 0.f; }

    const uint4* Wi[3];
#pragma unroll
    for (int g = 0; g < 3; g++) Wi[g] = Wib + (size_t)(g * S + c) * 1024;

#pragma unroll 1
    for (int i = 0; i < 4; i++) {
        int jc = t + 256 * i;  // 0..1023
        float4 av[8];
#pragma unroll
        for (int m = 0; m < 8; m++) av[m] = a[8 * jc + m];
#pragma unroll
        for (int g = 0; g < 3; g++) {
            uint4 w = Wi[g][jc];
            DOT8(accI[g], w, av)
        }
    }

    const uint4* Wh[3];
#pragma unroll
    for (int g = 0; g < 3; g++) Wh[g] = Whhb + (size_t)(g * S + c) * 512;

#pragma unroll 1
    for (int i = 0; i < 2; i++) {
        int jc = t + 256 * i;  // 0..511
        float4 hv[8];
#pragma unroll
        for (int m = 0; m < 8; m++) hv[m] = hcur[8 * jc + m];
#pragma unroll
        for (int g = 0; g < 3; g++) {
            uint4 w = Wh[g][jc];
            DOT8(accH[g], w, hv)
        }
    }

    gru_epilogue(accI, accH, c, t, hcur, hnext);
}

__global__ void enc_k(const float4* __restrict__ h, float* __restrict__ enc) {
    int idx = blockIdx.x * 256 + threadIdx.x;  // 0..16383
    int n = idx >> 12;
    int k = idx & (S - 1);
    enc[idx] = ((const float*)h)[k * 4 + n];
}

__global__ __launch_bounds__(256) void fc1_k(const float* __restrict__ W, const float* __restrict__ b,
                                             const float* __restrict__ enc, float* __restrict__ x1) {
    int j = blockIdx.x, t = threadIdx.x;
    const float4* row = (const float4*)(W + (size_t)j * (4 * S));
    const float4* e4 = (const float4*)enc;
    float acc = 0.f;
#pragma unroll 4
    for (int i = 0; i < 16; i++) {
        int m = t + 256 * i;
        float4 w = row[m];
        float4 e = e4[m];
        acc += w.x * e.x + w.y * e.y + w.z * e.z + w.w * e.w;
    }
    acc = wave_reduce_add(acc);
    __shared__ float red[4];
    if ((t & 63) == 0) red[t >> 6] = acc;
    __syncthreads();
    if (t == 0) x1[j] = red[0] + red[1] + red[2] + red[3] + b[j];
}

__global__ __launch_bounds__(256) void fc2_k(const float* __restrict__ W, const float* __restrict__ b,
                                             const float* __restrict__ x1, float* __restrict__ out) {
    int t = threadIdx.x;
    const float4* x4 = (const float4*)x1;
    const float4* w0 = (const float4*)W;
    const float4* w1 = (const float4*)(W + S);
    float a0 = 0.f, a1 = 0.f;
#pragma unroll
    for (int i = 0; i < 4; i++) {
        int m = t + 256 * i;
        float4 x = x4[m];
        float4 u = w0[m];
        float4 v = w1[m];
        a0 += u.x * x.x + u.y * x.y + u.z * x.z + u.w * x.w;
        a1 += v.x * x.x + v.y * x.y + v.z * x.z + v.w * x.w;
    }
    a0 = wave_reduce_add(a0);
    a1 = wave_reduce_add(a1);
    __shared__ float red0[4], red1[4];
    int lane = t & 63, wid = t >> 6;
    if (lane == 0) { red0[wid] = a0; red1[wid] = a1; }
    __syncthreads();
    if (t == 0) {
        float l0 = red0[0] + red0[1] + red0[2] + red0[3] + b[0];
        float l1 = red1[0] + red1[1] + red1[2] + red1[3] + b[1];
        float m = fmaxf(l0, l1);
        float ls = m + logf(expf(l0 - m) + expf(l1 - m));
        out[0] = l0 - ls;
        out[1] = l1 - ls;
    }
}

extern "C" void kernel_launch(void* const* d_in, const int* in_sizes, int n_in,
                              void* d_out, int out_size, void* d_ws, size_t ws_size,
                              hipStream_t stream) {
    const float* A_out = (const float*)d_in[0];
    const float* A_in  = (const float*)d_in[1];
    const float* ann   = (const float*)d_in[2];
    const float* W_ih  = (const float*)d_in[3];
    const float* W_hh  = (const float*)d_in[4];
    const float* fc1_w = (const float*)d_in[5];
    const float* fc1_b = (const float*)d_in[6];
    const float* fc2_w = (const float*)d_in[7];
    const float* fc2_b = (const float*)d_in[8];
    float* out = (float*)d_out;

    char* ws = (char*)d_ws;
    uint4* Wib  = (uint4*)ws;                        // 12288*1024*16 B = 201.3 MB
    uint4* Whhb = (uint4*)(ws + (size_t)12288 * 1024 * 16);  // 100.7 MB
    char* ws2 = ws + (size_t)12288 * 1024 * 16 + (size_t)12288 * 512 * 16;
    float4* hA  = (float4*)ws2;           // 4096 float4 = 64 KB
    float4* hB  = hA + S;                 // 64 KB
    float4* a_t = hB + S;                 // 8192 float4 = 128 KB
    float* enc  = (float*)(a_t + 2 * S);  // 64 KB
    float* x1   = enc + 4 * S;            // 16 KB

    init_h_k<<<S / 256, 256, 0, stream>>>(ann, hA);

    for (int step = 0; step < 8; step++) {
        float4* cur = (step & 1) ? hB : hA;
        float4* nxt = (step & 1) ? hA : hB;
        compute_a_k<<<2 * S / 256, 256, 0, stream>>>(A_out, A_in, cur, a_t);
        if (step == 0) {
            gru_conv_k<<<S, 256, 0, stream>>>(W_ih, W_hh, Wib, Whhb, a_t, cur, nxt);
        } else {
            gru_bf16_k<<<S, 256, 0, stream>>>(Wib, Whhb, a_t, cur, nxt);
        }
    }
    enc_k<<<4 * S / 256, 256, 0, stream>>>(hA, enc);
    fc1_k<<<S, 256, 0, stream>>>(fc1_w, fc1_b, enc, x1);
    fc2_k<<<1, 256, 0, stream>>>(fc2_w, fc2_b, x1, out);
}